// Round 10
// baseline (160.816 us; speedup 1.0000x reference)
//
#include <hip/hip_runtime.h>
#include <hip/hip_bf16.h>
#include <math.h>

#define B_ROWS 4096
#define D_DIM 512
#define TWO_B 8192
#define HW_N 256
#define BASE_T 0.07f
#define ALPHA_C 0.5f
#define LOG2E 1.44269504088896340736f
#define NSLICE 256

typedef float v4f __attribute__((ext_vector_type(4)));

__device__ __forceinline__ float fast_exp2(float x) {
#if __has_builtin(__builtin_amdgcn_exp2f)
    return __builtin_amdgcn_exp2f(x);
#else
    return exp2f(x);
#endif
}

// ---------------------------------------------------------------------------
// Kernel 1: normalize, temps, pos_sim; write X as packed fp8 e4m3 (OCP).
// Block 0 thread 0 zeroes out[0] for the finish kernel's atomic.
// ---------------------------------------------------------------------------
__global__ __launch_bounds__(256) void prep_kernel(
    const float* __restrict__ emb1, const float* __restrict__ emb2,
    const float* __restrict__ att, unsigned short* __restrict__ X8,
    float* __restrict__ inv_temp, float* __restrict__ pos,
    float* __restrict__ out)
{
    const int b = blockIdx.x;
    const int t = threadIdx.x;
    const float2 a1 = ((const float2*)(emb1 + (size_t)b * D_DIM))[t];
    const float2 a2 = ((const float2*)(emb2 + (size_t)b * D_DIM))[t];
    float av = att[(size_t)b * HW_N + t];
    float s1  = a1.x * a1.x + a1.y * a1.y;
    float s2  = a2.x * a2.x + a2.y * a2.y;
    float s12 = a1.x * a2.x + a1.y * a2.y;
    #pragma unroll
    for (int m = 1; m < 64; m <<= 1) {
        s1  += __shfl_xor(s1, m, 64);
        s2  += __shfl_xor(s2, m, 64);
        s12 += __shfl_xor(s12, m, 64);
        av  += __shfl_xor(av, m, 64);
    }
    __shared__ float red[4][4];
    const int w = t >> 6, lane = t & 63;
    if (lane == 0) { red[w][0] = s1; red[w][1] = s2; red[w][2] = s12; red[w][3] = av; }
    __syncthreads();
    const float T1  = red[0][0] + red[1][0] + red[2][0] + red[3][0];
    const float T2  = red[0][1] + red[1][1] + red[2][1] + red[3][1];
    const float T12 = red[0][2] + red[1][2] + red[2][2] + red[3][2];
    const float Ta  = red[0][3] + red[1][3] + red[2][3] + red[3][3];
    const float i1 = 1.0f / fmaxf(sqrtf(T1), 1e-12f);
    const float i2 = 1.0f / fmaxf(sqrtf(T2), 1e-12f);
    const float it = 1.0f / (BASE_T * (1.0f + ALPHA_C * (Ta * (1.0f / 256.0f))));
    const int p1 = __builtin_amdgcn_cvt_pk_fp8_f32(a1.x * i1, a1.y * i1, 0, false);
    const int p2 = __builtin_amdgcn_cvt_pk_fp8_f32(a2.x * i2, a2.y * i2, 0, false);
    X8[(size_t)b * 256 + t]            = (unsigned short)(p1 & 0xffff);
    X8[(size_t)(b + B_ROWS) * 256 + t] = (unsigned short)(p2 & 0xffff);
    if (t == 0) {
        inv_temp[b] = it * LOG2E;
        inv_temp[b + B_ROWS] = it * LOG2E;
        pos[b] = (T12 * i1 * i2) * it;       // ln units, exact fp32
        if (b == 0) out[0] = 0.0f;
    }
}

// ---------------------------------------------------------------------------
// Kernel 2: triangular Gram (rb<=cb) in FP8 e4m3 — R14: BARRIER-FREE body.
// Evidence: every per-K-step-barrier structure (R2/R9/R12/R13) lands >=45us
// while MFMA pipe ~17us and LDS pipe ~19us -> sync cadence is the invariant
// cost. K=512 fits in LDS: stage FULL A+B tiles (64KB+64KB = 128KB, proven
// viable by the m201 256^2 example's 128KB) with 16 glds/wave, then ONE
// __syncthreads(), then 128 MFMAs/wave straight-line (LDS read-only after
// the barrier -> no further sync), then store epilogue.
// 8 waves (2Mx4N), per-wave 64x32 out, acc[4][2]=32 VGPR; 1 blk/CU,
// ~8-9 sequential rounds/CU. Staging/read swizzle = R10's proven pair:
//   stage: srow=w*16+lr, su=(lane&3)^((lr>>1)&3), dest linear w*1024+l*16
//   read:  row r (r&15=t), slot pu=(s*2+(quad>>1))^((t>>1)&3), half quad&1
// Epilogue: 256 partial slices, exact cover (no pre-zero):
//   rows of (rb,cb): slice 4*cb+wn;  cols: slice 4*rb+2*wm+(mi>>1).
//   For row-index-block ri: row-writes fill [4ri,256), col-writes [0,4ri).
// ---------------------------------------------------------------------------
__device__ __forceinline__ void gload_lds16(const void* g, void* s) {
    __builtin_amdgcn_global_load_lds(
        (const __attribute__((address_space(1))) unsigned int*)g,
        (__attribute__((address_space(3))) unsigned int*)s,
        16, 0, 0);
}

__global__ __launch_bounds__(512, 2) void gram_kernel(
    const unsigned char* __restrict__ X8,
    const float* __restrict__ inv_temp,
    float* __restrict__ partial)
{
    // --- XCD-contiguous remap: 2080 = 8 XCDs x 260 contiguous tri-ids ---
    const int bid = (blockIdx.x & 7) * 260 + (blockIdx.x >> 3);
    // --- triangular index (64 tile-rows): bid -> (rb, cb), rb <= cb ---
    int rb = (int)((129.0f - sqrtf(129.0f * 129.0f - 8.0f * (float)bid)) * 0.5f);
    rb = rb < 0 ? 0 : (rb > 63 ? 63 : rb);
    while (rb > 0 && (rb * (129 - rb)) / 2 > bid) rb--;
    while (rb < 63 && ((rb + 1) * (129 - (rb + 1))) / 2 <= bid) rb++;
    const int cb = rb + (bid - (rb * (129 - rb)) / 2);

    // FULL K: 8 windows x 128 rows x 64 B per matrix = 64 KB each
    __shared__ unsigned char smA[8][8192];
    __shared__ unsigned char smB[8][8192];

    const int rowBase = rb * 128;
    const int colBase = cb * 128;

    const int tid  = threadIdx.x;
    const int w    = tid >> 6;      // 0..7
    const int lane = tid & 63;
    const int quad = lane >> 4;
    const int t    = lane & 15;
    const int wm   = w >> 2;        // 0..1 (row half, 64 rows)
    const int wn   = w & 3;         // 0..3 (col quarter, 32 cols)

    // staging roles (R10-proven): wave w covers rows w*16..w*16+15 per glds
    const int lr = lane >> 2;                    // 0..15 row within chunk
    const int su = (lane & 3) ^ ((lr >> 1) & 3); // pre-swizzled source unit
    const int srow = w * 16 + lr;                // 0..127

    const unsigned char* Arow0 = X8 + (size_t)rowBase * D_DIM;
    const unsigned char* Brow0 = X8 + (size_t)colBase * D_DIM;

    // ---- stage EVERYTHING: 8 k-windows x (1 A-glds + 1 B-glds) per wave ----
    #pragma unroll
    for (int kw = 0; kw < 8; kw++) {
        const size_t src = (size_t)srow * D_DIM + kw * 64 + su * 16;
        gload_lds16(Arow0 + src, &smA[kw][w * 1024]);
        gload_lds16(Brow0 + src, &smB[kw][w * 1024]);
    }
    __syncthreads();   // the ONLY barrier (compiler emits vmcnt(0) drain)

    // ---- straight-line compute: 8 windows x 2 slices x 8 MFMAs ----
    v4f acc[4][2];
    #pragma unroll
    for (int a = 0; a < 4; a++)
        #pragma unroll
        for (int b2 = 0; b2 < 2; b2++)
            acc[a][b2] = v4f{0.0f, 0.0f, 0.0f, 0.0f};

    const int hb = (t >> 1) & 3;             // read-side swizzle key
    const int aBase = (wm * 64 + t) * 64;    // + mi*1024
    const int bBase = (wn * 32 + t) * 64;    // + ni*1024

    #pragma unroll
    for (int kw = 0; kw < 8; kw++) {
        #pragma unroll
        for (int s = 0; s < 2; s++) {
            const int pu = (s * 2 + (quad >> 1)) ^ hb;
            const int off = pu * 16 + (quad & 1) * 8;
            long aF[4], bF[2];
            #pragma unroll
            for (int mi = 0; mi < 4; mi++)
                aF[mi] = *(const long*)&smA[kw][aBase + mi * 1024 + off];
            #pragma unroll
            for (int ni = 0; ni < 2; ni++)
                bF[ni] = *(const long*)&smB[kw][bBase + ni * 1024 + off];
            #pragma unroll
            for (int mi = 0; mi < 4; mi++)
                #pragma unroll
                for (int ni = 0; ni < 2; ni++)
                    acc[mi][ni] = __builtin_amdgcn_mfma_f32_16x16x32_fp8_fp8(
                        aF[mi], bF[ni], acc[mi][ni], 0, 0, 0);
        }
    }

    // ---- Epilogue 1: row sums (temp_i) -> partial slice 4*cb+wn ----
    v4f itv[4];
    #pragma unroll
    for (int mi = 0; mi < 4; mi++)
        itv[mi] = *(const v4f*)&inv_temp[rowBase + wm * 64 + mi * 16 + quad * 4];

    float* prow = partial + (size_t)(cb * 4 + wn) * TWO_B;
    #pragma unroll
    for (int mi = 0; mi < 4; mi++) {
        #pragma unroll
        for (int r = 0; r < 4; r++) {
            const int i = rowBase + wm * 64 + mi * 16 + quad * 4 + r;
            const float it = itv[mi][r];
            float s = 0.0f;
            #pragma unroll
            for (int ni = 0; ni < 2; ni++) {
                const int j = colBase + wn * 32 + ni * 16 + t;
                const float v = fast_exp2(acc[mi][ni][r] * it);
                s += (i == j) ? 0.0f : v;
            }
            s += __shfl_xor(s, 1, 64);
            s += __shfl_xor(s, 2, 64);
            s += __shfl_xor(s, 4, 64);
            s += __shfl_xor(s, 8, 64);
            if (t == 0) prow[i] = s;
        }
    }

    // ---- Epilogue 2 (off-diag): col sums (temp_j), mi-half split ----
    // slices 4*rb + 2*wm + {0,1}
    if (rb != cb) {
        float itj[2];
        float csL[2] = {0.0f, 0.0f};
        float csH[2] = {0.0f, 0.0f};
        #pragma unroll
        for (int ni = 0; ni < 2; ni++)
            itj[ni] = inv_temp[colBase + wn * 32 + ni * 16 + t];
        #pragma unroll
        for (int mi = 0; mi < 2; mi++)
            #pragma unroll
            for (int r = 0; r < 4; r++)
                #pragma unroll
                for (int ni = 0; ni < 2; ni++)
                    csL[ni] += fast_exp2(acc[mi][ni][r] * itj[ni]);
        #pragma unroll
        for (int mi = 2; mi < 4; mi++)
            #pragma unroll
            for (int r = 0; r < 4; r++)
                #pragma unroll
                for (int ni = 0; ni < 2; ni++)
                    csH[ni] += fast_exp2(acc[mi][ni][r] * itj[ni]);
        float* pL = partial + (size_t)(rb * 4 + wm * 2 + 0) * TWO_B;
        float* pH = partial + (size_t)(rb * 4 + wm * 2 + 1) * TWO_B;
        #pragma unroll
        for (int ni = 0; ni < 2; ni++) {
            csL[ni] += __shfl_xor(csL[ni], 16, 64);
            csL[ni] += __shfl_xor(csL[ni], 32, 64);
            csH[ni] += __shfl_xor(csH[ni], 16, 64);
            csH[ni] += __shfl_xor(csH[ni], 32, 64);
            if (quad == 0) {
                const int j = colBase + wn * 32 + ni * 16 + t;
                pL[j] = csL[ni];
                pH[j] = csH[ni];
            }
        }
    }
}

// ---------------------------------------------------------------------------
// Kernel 3: denom = sum of 256 slices; loss_i = log(denom) - pos;
// block sum atomically accumulated into out[0] (zeroed by prep_kernel).
// ---------------------------------------------------------------------------
__global__ __launch_bounds__(256) void finishk(
    const float* __restrict__ partial, const float* __restrict__ pos,
    float* __restrict__ out)
{
    const int i = blockIdx.x * 256 + threadIdx.x;
    float d = 0.0f;
    #pragma unroll 8
    for (int s = 0; s < NSLICE; s++) d += partial[(size_t)s * TWO_B + i];
    float li = logf(d) - pos[i & (B_ROWS - 1)];
    #pragma unroll
    for (int m = 1; m < 64; m <<= 1) li += __shfl_xor(li, m, 64);
    __shared__ float red[4];
    const int w = threadIdx.x >> 6, lane = threadIdx.x & 63;
    if (lane == 0) red[w] = li;
    __syncthreads();
    if (threadIdx.x == 0)
        atomicAdd(out, (red[0] + red[1] + red[2] + red[3]) * (1.0f / 8192.0f));
}

// ---------------------------------------------------------------------------
extern "C" void kernel_launch(void* const* d_in, const int* in_sizes, int n_in,
                              void* d_out, int out_size, void* d_ws, size_t ws_size,
                              hipStream_t stream) {
    const float* emb1 = (const float*)d_in[0];
    const float* emb2 = (const float*)d_in[1];
    const float* att  = (const float*)d_in[2];
    float* out = (float*)d_out;

    char* ws = (char*)d_ws;
    // layout: X8 fp8 [8192*512] = 4,194,304 B
    //         inv_temp f32 [8192]      -> +32,768
    //         pos f32 [4096]           -> +16,384
    //         partial f32 [256*8192]   -> +8,388,608
    unsigned short* X8 = (unsigned short*)ws;
    float* inv_temp    = (float*)(ws + 4194304);
    float* pos         = (float*)(ws + 4194304 + 32768);
    float* partial     = (float*)(ws + 4194304 + 32768 + 16384);

    prep_kernel<<<B_ROWS, 256, 0, stream>>>(emb1, emb2, att, X8, inv_temp, pos, out);
    gram_kernel<<<2080, 512, 0, stream>>>((const unsigned char*)X8, inv_temp, partial);
    finishk<<<TWO_B / 256, 256, 0, stream>>>(partial, pos, out);
}

// Round 12
// 139.680 us; speedup vs baseline: 1.1513x; 1.1513x over previous
//
#include <hip/hip_runtime.h>
#include <hip/hip_bf16.h>
#include <math.h>

#define B_ROWS 4096
#define D_DIM 512
#define TWO_B 8192
#define HW_N 256
#define BASE_T 0.07f
#define ALPHA_C 0.5f
#define LOG2E 1.44269504088896340736f

typedef float v4f __attribute__((ext_vector_type(4)));

__device__ __forceinline__ float fast_exp2(float x) {
#if __has_builtin(__builtin_amdgcn_exp2f)
    return __builtin_amdgcn_exp2f(x);
#else
    return exp2f(x);
#endif
}

// ---------------------------------------------------------------------------
// Kernel 1: normalize, temps, pos_sim; write X as packed fp8 e4m3 (OCP).
// Block 0 thread 0 zeroes out[0] for the finish kernel's atomic.
// ---------------------------------------------------------------------------
__global__ __launch_bounds__(256) void prep_kernel(
    const float* __restrict__ emb1, const float* __restrict__ emb2,
    const float* __restrict__ att, unsigned short* __restrict__ X8,
    float* __restrict__ inv_temp, float* __restrict__ pos,
    float* __restrict__ out)
{
    const int b = blockIdx.x;
    const int t = threadIdx.x;
    const float2 a1 = ((const float2*)(emb1 + (size_t)b * D_DIM))[t];
    const float2 a2 = ((const float2*)(emb2 + (size_t)b * D_DIM))[t];
    float av = att[(size_t)b * HW_N + t];
    float s1  = a1.x * a1.x + a1.y * a1.y;
    float s2  = a2.x * a2.x + a2.y * a2.y;
    float s12 = a1.x * a2.x + a1.y * a2.y;
    #pragma unroll
    for (int m = 1; m < 64; m <<= 1) {
        s1  += __shfl_xor(s1, m, 64);
        s2  += __shfl_xor(s2, m, 64);
        s12 += __shfl_xor(s12, m, 64);
        av  += __shfl_xor(av, m, 64);
    }
    __shared__ float red[4][4];
    const int w = t >> 6, lane = t & 63;
    if (lane == 0) { red[w][0] = s1; red[w][1] = s2; red[w][2] = s12; red[w][3] = av; }
    __syncthreads();
    const float T1  = red[0][0] + red[1][0] + red[2][0] + red[3][0];
    const float T2  = red[0][1] + red[1][1] + red[2][1] + red[3][1];
    const float T12 = red[0][2] + red[1][2] + red[2][2] + red[3][2];
    const float Ta  = red[0][3] + red[1][3] + red[2][3] + red[3][3];
    const float i1 = 1.0f / fmaxf(sqrtf(T1), 1e-12f);
    const float i2 = 1.0f / fmaxf(sqrtf(T2), 1e-12f);
    const float it = 1.0f / (BASE_T * (1.0f + ALPHA_C * (Ta * (1.0f / 256.0f))));
    const int p1 = __builtin_amdgcn_cvt_pk_fp8_f32(a1.x * i1, a1.y * i1, 0, false);
    const int p2 = __builtin_amdgcn_cvt_pk_fp8_f32(a2.x * i2, a2.y * i2, 0, false);
    X8[(size_t)b * 256 + t]            = (unsigned short)(p1 & 0xffff);
    X8[(size_t)(b + B_ROWS) * 256 + t] = (unsigned short)(p2 & 0xffff);
    if (t == 0) {
        inv_temp[b] = it * LOG2E;
        inv_temp[b + B_ROWS] = it * LOG2E;
        pos[b] = (T12 * i1 * i2) * it;       // ln units, exact fp32
        if (b == 0) out[0] = 0.0f;
    }
}

// ---------------------------------------------------------------------------
// Kernel 2: triangular Gram (rb<=cb) in FP8 e4m3 — R16 = R15 resubmitted
// (R15 never ran: container infra failure, same signature as R0 which later
// benched clean). R2's proven 45.2us kernel + PHASE-DIVERSITY package:
//  (a) __launch_bounds__(256,5): 5 blocks/CU (LDS 5x32KB = 160KB exact,
//      VGPR 72 < 96 cap, no spill) — blocks/CU is the one lever that ever
//      moved gram (R1->R2: 64->45us at 2->4 blocks/CU).
//  (b) entry s_sleep stagger ((bid>>3)%5 x ~450cy): co-resident blocks run
//      identical code and launch lockstep -> all waves on a CU hit the same
//      phase (all-MFMA / all-epilogue-VALU / all-stage) -> pipes SERIALIZE.
//      Pipe math: MFMA 16.8us + VALU ~13us + LDS ~12us: sum 42 ~= measured
//      45; max 17. Stagger converts first-batch sum toward max.
// Bank-conflict counter re-audit: 4.26M = 4 cy x 512 b64 reads/block =
// structural 4-pass minimum of a 512B wave-read at the 128 B/cy LDS
// ceiling — not a fixable conflict.
// ---------------------------------------------------------------------------
__device__ __forceinline__ void gload_lds16(const void* g, void* s) {
    __builtin_amdgcn_global_load_lds(
        (const __attribute__((address_space(1))) unsigned int*)g,
        (__attribute__((address_space(3))) unsigned int*)s,
        16, 0, 0);
}

__global__ __launch_bounds__(256, 5) void gram_kernel(
    const unsigned char* __restrict__ X8,
    const float* __restrict__ inv_temp,
    float* __restrict__ partial)
{
    // --- phase stagger: desync co-resident blocks (~450 cy granularity) ---
    {
        const int stg = (int)((blockIdx.x >> 3) % 5u);
        for (int z = 0; z < stg; z++) __builtin_amdgcn_s_sleep(7);
    }

    // --- XCD-contiguous remap: 2080 = 8 XCDs x 260 contiguous tri-ids ---
    const int bid = (blockIdx.x & 7) * 260 + (blockIdx.x >> 3);
    // --- triangular index: bid -> (rb, cb), rb <= cb ---
    int rb = (int)((129.0f - sqrtf(129.0f * 129.0f - 8.0f * (float)bid)) * 0.5f);
    rb = rb < 0 ? 0 : (rb > 63 ? 63 : rb);
    while (rb > 0 && (rb * (129 - rb)) / 2 > bid) rb--;
    while (rb < 63 && ((rb + 1) * (129 - (rb + 1))) / 2 <= bid) rb++;
    const int cb = rb + (bid - (rb * (129 - rb)) / 2);

    // double-buffered: 2 x 128 rows x 64 B per matrix = 32 KB total
    __shared__ unsigned char smA[2][8192];
    __shared__ unsigned char smB[2][8192];

    const int rowBase = rb * 128;
    const int colBase = cb * 128;

    const int tid  = threadIdx.x;
    const int w    = tid >> 6;
    const int lane = tid & 63;
    const int quad = lane >> 4;
    const int t    = lane & 15;
    const int wm   = w >> 1;
    const int wn   = w & 1;

    // staging roles: each glds covers 16 rows x 4 units(16B) = 1 KB
    const int lr = lane >> 2;   // 0..15 (row within group)
    const int su = lane & 3;    // 0..3  (16B unit within row)

    const unsigned char* Arow0 = X8 + (size_t)rowBase * D_DIM;
    const unsigned char* Brow0 = X8 + (size_t)colBase * D_DIM;

    v4f acc[4][4];
    #pragma unroll
    for (int a = 0; a < 4; a++)
        #pragma unroll
        for (int b2 = 0; b2 < 4; b2++)
            acc[a][b2] = v4f{0.0f, 0.0f, 0.0f, 0.0f};

    const int hb = (t >> 1) & 3;            // read-side swizzle key
    const int aBase = (wm * 64 + t) * 64;   // LDS row base (A), rows mi*16 apart
    const int bBase = (wn * 64 + t) * 64;

    // ---- prologue: stage tile 0 into buffer 0 ----
    #pragma unroll
    for (int j = 0; j < 2; j++) {
        const int g = w * 2 + j;            // row group 0..7 (16 rows)
        const int r = g * 16 + lr;
        const int gc = su ^ ((r >> 1) & 3); // XOR swizzle via global unit
        gload_lds16(Arow0 + (size_t)r * D_DIM + gc * 16, &smA[0][g * 1024]);
        gload_lds16(Brow0 + (size_t)r * D_DIM + gc * 16, &smB[0][g * 1024]);
    }
    __syncthreads();

    // ---- 8-tile double-buffered main loop (BK=64) ----
    #pragma unroll
    for (int p = 0; p < 8; p++) {
        const int cur = p & 1;

        // issue next-tile staging first (hidden under this tile's MFMAs)
        if (p < 7) {
            const int kk = (p + 1) * 64;
            #pragma unroll
            for (int j = 0; j < 2; j++) {
                const int g = w * 2 + j;
                const int r = g * 16 + lr;
                const int gc = su ^ ((r >> 1) & 3);
                gload_lds16(Arow0 + (size_t)r * D_DIM + kk + gc * 16, &smA[cur ^ 1][g * 1024]);
                gload_lds16(Brow0 + (size_t)r * D_DIM + kk + gc * 16, &smB[cur ^ 1][g * 1024]);
            }
        }

        // compute current tile: 2 k-slices of 32 B
        #pragma unroll
        for (int s = 0; s < 2; s++) {
            const int pu = (s * 2 + (quad >> 1)) ^ hb;
            const int off = pu * 16 + (quad & 1) * 8;
            long aF[4], bF[4];
            #pragma unroll
            for (int mi = 0; mi < 4; mi++)
                aF[mi] = *(const long*)&smA[cur][aBase + mi * 1024 + off];
            #pragma unroll
            for (int ni = 0; ni < 4; ni++)
                bF[ni] = *(const long*)&smB[cur][bBase + ni * 1024 + off];
            #pragma unroll
            for (int mi = 0; mi < 4; mi++)
                #pragma unroll
                for (int ni = 0; ni < 4; ni++)
                    acc[mi][ni] = __builtin_amdgcn_mfma_f32_16x16x32_fp8_fp8(
                        aF[mi], bF[ni], acc[mi][ni], 0, 0, 0);
        }

        // one barrier per tile: drains stage(p+1), releases cur for p+1
        __syncthreads();
    }

    // ---- Epilogue 1: row sums (temp_i), slice 2*cb+wn ----
    v4f itv[4];
    #pragma unroll
    for (int mi = 0; mi < 4; mi++)
        itv[mi] = *(const v4f*)&inv_temp[rowBase + wm * 64 + mi * 16 + quad * 4];

    float* prow = partial + (size_t)(cb * 2 + wn) * TWO_B;
    #pragma unroll
    for (int mi = 0; mi < 4; mi++) {
        #pragma unroll
        for (int r = 0; r < 4; r++) {
            const int i = rowBase + wm * 64 + mi * 16 + quad * 4 + r;
            const float it = itv[mi][r];
            float s = 0.0f;
            #pragma unroll
            for (int ni = 0; ni < 4; ni++) {
                const int j = colBase + wn * 64 + ni * 16 + t;
                const float v = fast_exp2(acc[mi][ni][r] * it);
                s += (i == j) ? 0.0f : v;
            }
            s += __shfl_xor(s, 1, 64);
            s += __shfl_xor(s, 2, 64);
            s += __shfl_xor(s, 4, 64);
            s += __shfl_xor(s, 8, 64);
            if (t == 0) prow[i] = s;
        }
    }

    // ---- Epilogue 2 (off-diag): col sums (temp_j), slice 2*rb+wm ----
    if (rb != cb) {
        float itj[4];
        float cs[4] = {0.0f, 0.0f, 0.0f, 0.0f};
        #pragma unroll
        for (int ni = 0; ni < 4; ni++)
            itj[ni] = inv_temp[colBase + wn * 64 + ni * 16 + t];
        #pragma unroll
        for (int mi = 0; mi < 4; mi++)
            #pragma unroll
            for (int r = 0; r < 4; r++)
                #pragma unroll
                for (int ni = 0; ni < 4; ni++)
                    cs[ni] += fast_exp2(acc[mi][ni][r] * itj[ni]);
        float* pcol = partial + (size_t)(rb * 2 + wm) * TWO_B;
        #pragma unroll
        for (int ni = 0; ni < 4; ni++) {
            cs[ni] += __shfl_xor(cs[ni], 16, 64);
            cs[ni] += __shfl_xor(cs[ni], 32, 64);
            if (quad == 0) pcol[colBase + wn * 64 + ni * 16 + t] = cs[ni];
        }
    }
}

// ---------------------------------------------------------------------------
// Kernel 3: denom = sum of 128 slices; loss_i = log(denom) - pos;
// block sum atomically accumulated into out[0] (zeroed by prep_kernel).
// ---------------------------------------------------------------------------
__global__ __launch_bounds__(256) void finishk(
    const float* __restrict__ partial, const float* __restrict__ pos,
    float* __restrict__ out)
{
    const int i = blockIdx.x * 256 + threadIdx.x;
    float d = 0.0f;
    #pragma unroll 8
    for (int s = 0; s < 128; s++) d += partial[(size_t)s * TWO_B + i];
    float li = logf(d) - pos[i & (B_ROWS - 1)];
    #pragma unroll
    for (int m = 1; m < 64; m <<= 1) li += __shfl_xor(li, m, 64);
    __shared__ float red[4];
    const int w = threadIdx.x >> 6, lane = threadIdx.x & 63;
    if (lane == 0) red[w] = li;
    __syncthreads();
    if (threadIdx.x == 0)
        atomicAdd(out, (red[0] + red[1] + red[2] + red[3]) * (1.0f / 8192.0f));
}

// ---------------------------------------------------------------------------
extern "C" void kernel_launch(void* const* d_in, const int* in_sizes, int n_in,
                              void* d_out, int out_size, void* d_ws, size_t ws_size,
                              hipStream_t stream) {
    const float* emb1 = (const float*)d_in[0];
    const float* emb2 = (const float*)d_in[1];
    const float* att  = (const float*)d_in[2];
    float* out = (float*)d_out;

    char* ws = (char*)d_ws;
    // layout: X8 fp8 [8192*512] = 4,194,304 B
    //         inv_temp f32 [8192]      -> +32,768
    //         pos f32 [4096]           -> +16,384
    //         partial f32 [128*8192]   -> +4,194,304
    unsigned short* X8 = (unsigned short*)ws;
    float* inv_temp    = (float*)(ws + 4194304);
    float* pos         = (float*)(ws + 4194304 + 32768);
    float* partial     = (float*)(ws + 4194304 + 32768 + 16384);

    prep_kernel<<<B_ROWS, 256, 0, stream>>>(emb1, emb2, att, X8, inv_temp, pos, out);
    gram_kernel<<<2080, 256, 0, stream>>>((const unsigned char*)X8, inv_temp, partial);
    finishk<<<TWO_B / 256, 256, 0, stream>>>(partial, pos, out);
}

// Round 13
// 120.241 us; speedup vs baseline: 1.3374x; 1.1617x over previous
//
#include <hip/hip_runtime.h>
#include <hip/hip_bf16.h>
#include <math.h>

#define B_ROWS 4096
#define D_DIM 512
#define TWO_B 8192
#define HW_N 256
#define BASE_T 0.07f
#define ALPHA_C 0.5f
#define LOG2E 1.44269504088896340736f

typedef float v4f __attribute__((ext_vector_type(4)));

__device__ __forceinline__ float fast_exp2(float x) {
#if __has_builtin(__builtin_amdgcn_exp2f)
    return __builtin_amdgcn_exp2f(x);
#else
    return exp2f(x);
#endif
}

// ---------------------------------------------------------------------------
// Kernel 1: normalize, temps, pos_sim; write X as packed fp8 e4m3 (OCP).
// Block 0 thread 0 zeroes out[0] for the finish kernel's atomic.
// ---------------------------------------------------------------------------
__global__ __launch_bounds__(256) void prep_kernel(
    const float* __restrict__ emb1, const float* __restrict__ emb2,
    const float* __restrict__ att, unsigned short* __restrict__ X8,
    float* __restrict__ inv_temp, float* __restrict__ pos,
    float* __restrict__ out)
{
    const int b = blockIdx.x;
    const int t = threadIdx.x;
    const float2 a1 = ((const float2*)(emb1 + (size_t)b * D_DIM))[t];
    const float2 a2 = ((const float2*)(emb2 + (size_t)b * D_DIM))[t];
    float av = att[(size_t)b * HW_N + t];
    float s1  = a1.x * a1.x + a1.y * a1.y;
    float s2  = a2.x * a2.x + a2.y * a2.y;
    float s12 = a1.x * a2.x + a1.y * a2.y;
    #pragma unroll
    for (int m = 1; m < 64; m <<= 1) {
        s1  += __shfl_xor(s1, m, 64);
        s2  += __shfl_xor(s2, m, 64);
        s12 += __shfl_xor(s12, m, 64);
        av  += __shfl_xor(av, m, 64);
    }
    __shared__ float red[4][4];
    const int w = t >> 6, lane = t & 63;
    if (lane == 0) { red[w][0] = s1; red[w][1] = s2; red[w][2] = s12; red[w][3] = av; }
    __syncthreads();
    const float T1  = red[0][0] + red[1][0] + red[2][0] + red[3][0];
    const float T2  = red[0][1] + red[1][1] + red[2][1] + red[3][1];
    const float T12 = red[0][2] + red[1][2] + red[2][2] + red[3][2];
    const float Ta  = red[0][3] + red[1][3] + red[2][3] + red[3][3];
    const float i1 = 1.0f / fmaxf(sqrtf(T1), 1e-12f);
    const float i2 = 1.0f / fmaxf(sqrtf(T2), 1e-12f);
    const float it = 1.0f / (BASE_T * (1.0f + ALPHA_C * (Ta * (1.0f / 256.0f))));
    const int p1 = __builtin_amdgcn_cvt_pk_fp8_f32(a1.x * i1, a1.y * i1, 0, false);
    const int p2 = __builtin_amdgcn_cvt_pk_fp8_f32(a2.x * i2, a2.y * i2, 0, false);
    X8[(size_t)b * 256 + t]            = (unsigned short)(p1 & 0xffff);
    X8[(size_t)(b + B_ROWS) * 256 + t] = (unsigned short)(p2 & 0xffff);
    if (t == 0) {
        inv_temp[b] = it * LOG2E;
        inv_temp[b + B_ROWS] = it * LOG2E;
        pos[b] = (T12 * i1 * i2) * it;       // ln units, exact fp32
        if (b == 0) out[0] = 0.0f;
    }
}

// ---------------------------------------------------------------------------
// Kernel 2: triangular Gram (rb<=cb) in FP8 e4m3 — R17: STAGGER-ONLY test.
// R16's (256,5) forced VGPR to 48 < acc's 64 -> scratch spill (FETCH 50MB /
// WRITE 56MB) and poisoned the phase-diversity experiment. m69: wave-slot
// VGPR granularity steps at {64,128,256} -> 4 blocks/CU is this kernel's
// occupancy ceiling. So: R2's proven 45.2us kernel, launch_bounds(256,4),
// ONE added variable — the entry stagger.
// Mechanism: co-resident blocks start lockstep, run identical code, finish
// together -> replacements inherit lockstep -> CU alternates all-MFMA /
// all-VALU / all-stage phases forever. Pipe math: sum 42us ~= measured 45;
// max 17. A one-time ~450cy x (bid%4) offset persists through the
// self-perpetuating schedule and converts sum toward max.
// ---------------------------------------------------------------------------
__device__ __forceinline__ void gload_lds16(const void* g, void* s) {
    __builtin_amdgcn_global_load_lds(
        (const __attribute__((address_space(1))) unsigned int*)g,
        (__attribute__((address_space(3))) unsigned int*)s,
        16, 0, 0);
}

__global__ __launch_bounds__(256, 4) void gram_kernel(
    const unsigned char* __restrict__ X8,
    const float* __restrict__ inv_temp,
    float* __restrict__ partial)
{
    // --- phase stagger: desync co-resident blocks (~450 cy granularity) ---
    {
        const int stg = (int)((blockIdx.x >> 3) & 3u);
        for (int z = 0; z < stg; z++) __builtin_amdgcn_s_sleep(7);
    }

    // --- XCD-contiguous remap: 2080 = 8 XCDs x 260 contiguous tri-ids ---
    const int bid = (blockIdx.x & 7) * 260 + (blockIdx.x >> 3);
    // --- triangular index: bid -> (rb, cb), rb <= cb ---
    int rb = (int)((129.0f - sqrtf(129.0f * 129.0f - 8.0f * (float)bid)) * 0.5f);
    rb = rb < 0 ? 0 : (rb > 63 ? 63 : rb);
    while (rb > 0 && (rb * (129 - rb)) / 2 > bid) rb--;
    while (rb < 63 && ((rb + 1) * (129 - (rb + 1))) / 2 <= bid) rb++;
    const int cb = rb + (bid - (rb * (129 - rb)) / 2);

    // double-buffered: 2 x 128 rows x 64 B per matrix = 32 KB total
    __shared__ unsigned char smA[2][8192];
    __shared__ unsigned char smB[2][8192];

    const int rowBase = rb * 128;
    const int colBase = cb * 128;

    const int tid  = threadIdx.x;
    const int w    = tid >> 6;
    const int lane = tid & 63;
    const int quad = lane >> 4;
    const int t    = lane & 15;
    const int wm   = w >> 1;
    const int wn   = w & 1;

    // staging roles: each glds covers 16 rows x 4 units(16B) = 1 KB
    const int lr = lane >> 2;   // 0..15 (row within group)
    const int su = lane & 3;    // 0..3  (16B unit within row)

    const unsigned char* Arow0 = X8 + (size_t)rowBase * D_DIM;
    const unsigned char* Brow0 = X8 + (size_t)colBase * D_DIM;

    v4f acc[4][4];
    #pragma unroll
    for (int a = 0; a < 4; a++)
        #pragma unroll
        for (int b2 = 0; b2 < 4; b2++)
            acc[a][b2] = v4f{0.0f, 0.0f, 0.0f, 0.0f};

    const int hb = (t >> 1) & 3;            // read-side swizzle key
    const int aBase = (wm * 64 + t) * 64;   // LDS row base (A), rows mi*16 apart
    const int bBase = (wn * 64 + t) * 64;

    // ---- prologue: stage tile 0 into buffer 0 ----
    #pragma unroll
    for (int j = 0; j < 2; j++) {
        const int g = w * 2 + j;            // row group 0..7 (16 rows)
        const int r = g * 16 + lr;
        const int gc = su ^ ((r >> 1) & 3); // XOR swizzle via global unit
        gload_lds16(Arow0 + (size_t)r * D_DIM + gc * 16, &smA[0][g * 1024]);
        gload_lds16(Brow0 + (size_t)r * D_DIM + gc * 16, &smB[0][g * 1024]);
    }
    __syncthreads();

    // ---- 8-tile double-buffered main loop (BK=64) ----
    #pragma unroll
    for (int p = 0; p < 8; p++) {
        const int cur = p & 1;

        // issue next-tile staging first (hidden under this tile's MFMAs)
        if (p < 7) {
            const int kk = (p + 1) * 64;
            #pragma unroll
            for (int j = 0; j < 2; j++) {
                const int g = w * 2 + j;
                const int r = g * 16 + lr;
                const int gc = su ^ ((r >> 1) & 3);
                gload_lds16(Arow0 + (size_t)r * D_DIM + kk + gc * 16, &smA[cur ^ 1][g * 1024]);
                gload_lds16(Brow0 + (size_t)r * D_DIM + kk + gc * 16, &smB[cur ^ 1][g * 1024]);
            }
        }

        // compute current tile: 2 k-slices of 32 B
        #pragma unroll
        for (int s = 0; s < 2; s++) {
            const int pu = (s * 2 + (quad >> 1)) ^ hb;
            const int off = pu * 16 + (quad & 1) * 8;
            long aF[4], bF[4];
            #pragma unroll
            for (int mi = 0; mi < 4; mi++)
                aF[mi] = *(const long*)&smA[cur][aBase + mi * 1024 + off];
            #pragma unroll
            for (int ni = 0; ni < 4; ni++)
                bF[ni] = *(const long*)&smB[cur][bBase + ni * 1024 + off];
            #pragma unroll
            for (int mi = 0; mi < 4; mi++)
                #pragma unroll
                for (int ni = 0; ni < 4; ni++)
                    acc[mi][ni] = __builtin_amdgcn_mfma_f32_16x16x32_fp8_fp8(
                        aF[mi], bF[ni], acc[mi][ni], 0, 0, 0);
        }

        // one barrier per tile: drains stage(p+1), releases cur for p+1
        __syncthreads();
    }

    // ---- Epilogue 1: row sums (temp_i), slice 2*cb+wn ----
    v4f itv[4];
    #pragma unroll
    for (int mi = 0; mi < 4; mi++)
        itv[mi] = *(const v4f*)&inv_temp[rowBase + wm * 64 + mi * 16 + quad * 4];

    float* prow = partial + (size_t)(cb * 2 + wn) * TWO_B;
    #pragma unroll
    for (int mi = 0; mi < 4; mi++) {
        #pragma unroll
        for (int r = 0; r < 4; r++) {
            const int i = rowBase + wm * 64 + mi * 16 + quad * 4 + r;
            const float it = itv[mi][r];
            float s = 0.0f;
            #pragma unroll
            for (int ni = 0; ni < 4; ni++) {
                const int j = colBase + wn * 64 + ni * 16 + t;
                const float v = fast_exp2(acc[mi][ni][r] * it);
                s += (i == j) ? 0.0f : v;
            }
            s += __shfl_xor(s, 1, 64);
            s += __shfl_xor(s, 2, 64);
            s += __shfl_xor(s, 4, 64);
            s += __shfl_xor(s, 8, 64);
            if (t == 0) prow[i] = s;
        }
    }

    // ---- Epilogue 2 (off-diag): col sums (temp_j), slice 2*rb+wm ----
    if (rb != cb) {
        float itj[4];
        float cs[4] = {0.0f, 0.0f, 0.0f, 0.0f};
        #pragma unroll
        for (int ni = 0; ni < 4; ni++)
            itj[ni] = inv_temp[colBase + wn * 64 + ni * 16 + t];
        #pragma unroll
        for (int mi = 0; mi < 4; mi++)
            #pragma unroll
            for (int r = 0; r < 4; r++)
                #pragma unroll
                for (int ni = 0; ni < 4; ni++)
                    cs[ni] += fast_exp2(acc[mi][ni][r] * itj[ni]);
        float* pcol = partial + (size_t)(rb * 2 + wm) * TWO_B;
        #pragma unroll
        for (int ni = 0; ni < 4; ni++) {
            cs[ni] += __shfl_xor(cs[ni], 16, 64);
            cs[ni] += __shfl_xor(cs[ni], 32, 64);
            if (quad == 0) pcol[colBase + wn * 64 + ni * 16 + t] = cs[ni];
        }
    }
}

// ---------------------------------------------------------------------------
// Kernel 3: denom = sum of 128 slices; loss_i = log(denom) - pos;
// block sum atomically accumulated into out[0] (zeroed by prep_kernel).
// ---------------------------------------------------------------------------
__global__ __launch_bounds__(256) void finishk(
    const float* __restrict__ partial, const float* __restrict__ pos,
    float* __restrict__ out)
{
    const int i = blockIdx.x * 256 + threadIdx.x;
    float d = 0.0f;
    #pragma unroll 8
    for (int s = 0; s < 128; s++) d += partial[(size_t)s * TWO_B + i];
    float li = logf(d) - pos[i & (B_ROWS - 1)];
    #pragma unroll
    for (int m = 1; m < 64; m <<= 1) li += __shfl_xor(li, m, 64);
    __shared__ float red[4];
    const int w = threadIdx.x >> 6, lane = threadIdx.x & 63;
    if (lane == 0) red[w] = li;
    __syncthreads();
    if (threadIdx.x == 0)
        atomicAdd(out, (red[0] + red[1] + red[2] + red[3]) * (1.0f / 8192.0f));
}

// ---------------------------------------------------------------------------
extern "C" void kernel_launch(void* const* d_in, const int* in_sizes, int n_in,
                              void* d_out, int out_size, void* d_ws, size_t ws_size,
                              hipStream_t stream) {
    const float* emb1 = (const float*)d_in[0];
    const float* emb2 = (const float*)d_in[1];
    const float* att  = (const float*)d_in[2];
    float* out = (float*)d_out;

    char* ws = (char*)d_ws;
    // layout: X8 fp8 [8192*512] = 4,194,304 B
    //         inv_temp f32 [8192]      -> +32,768
    //         pos f32 [4096]           -> +16,384
    //         partial f32 [128*8192]   -> +4,194,304
    unsigned short* X8 = (unsigned short*)ws;
    float* inv_temp    = (float*)(ws + 4194304);
    float* pos         = (float*)(ws + 4194304 + 32768);
    float* partial     = (float*)(ws + 4194304 + 32768 + 16384);

    prep_kernel<<<B_ROWS, 256, 0, stream>>>(emb1, emb2, att, X8, inv_temp, pos, out);
    gram_kernel<<<2080, 256, 0, stream>>>((const unsigned char*)X8, inv_temp, partial);
    finishk<<<TWO_B / 256, 256, 0, stream>>>(partial, pos, out);
}